// Round 2
// baseline (272.102 us; speedup 1.0000x reference)
//
#include <hip/hip_runtime.h>
#include <math.h>

// ContextCluster, fp32, MI355X gfx950 — round 11.
// R10 analysis: both kernels LDS-pipe-bound (per-CU LDS data path, cost ~
// 12cyc/ds_read_b128, broadcast NOT free). cc_main: 576 LDS-cyc/k/CU vs 256
// VALU-cyc/k -> VALUBusy capped at 55%. cc_proj: 768 vs 192 -> ~125us vs
// 20.5us FMA floor.
// R11: W moves to the SCALAR path. Wave = 32ch(24oc) x 64px(lane); W rows are
// k-contiguous and wave-uniform -> s_load_dwordx8 into SGPRs (separate pipe,
// K$/L2). x: single ds_read_b32/k from [64px][33] (2-way, free). LDS pipe
// ~16% util -> VALU-bound (floors 41us + 20.5us). Cluster: lane=px and
// HEAD_DIM=32 => wave 0/1 = whole f-head, 2/3 = whole v-head in regs; pool
// via DPP-max (exact), sims in-reg; only v dumped (16.6KB). LDS 31.5KB.
// All accumulation orders unchanged -> bit-identical to R10.

#define TPB 256

template<int CTRL>
__device__ __forceinline__ float dpp_max(float v) {
    int s = __builtin_bit_cast(int, v);
    int p = __builtin_amdgcn_update_dpp(0, s, CTRL, 0xF, 0xF, true);
    return fmaxf(v, __builtin_bit_cast(float, p));
}

__global__ __launch_bounds__(TPB, 4)
void cc_main(const float* __restrict__ x,
             const float* __restrict__ Wf, const float* __restrict__ bf,
             const float* __restrict__ Wv, const float* __restrict__ bv,
             const float* __restrict__ salpha, const float* __restrict__ sbeta,
             float* __restrict__ disp)
{
    __shared__ __align__(16) float xch[64*33];      // [px][33k] chunk
    __shared__ __align__(16) float vd[2][64*33];    // v dump [n][33c] per head
    __shared__ __align__(16) float cfs[2][128];     // f centers [c*4+m]
    __shared__ __align__(16) float cvs[2][128];     // v centers [c*4+m]
    __shared__ float swb[2][256];                   // masked sims [m*64+n]
    __shared__ float2 bib[2][64];                   // (bvv, bi) per n
    __shared__ float cnts[2][4];
    __shared__ float aggs[2][132];                  // [m*33+c]

    const int t    = threadIdx.x;
    const int lane = t & 63;                        // = px n
    const int wid  = __builtin_amdgcn_readfirstlane(t >> 6);  // 0,1=f-heads; 2,3=v-heads
    const int he   = wid & 1;
    const int blk  = blockIdx.x;
    // XCD-partitioned decode (R10): XCD = blk&7 = f1 -> x slice L2-resident.
    const int f1   = blk & 7;
    const int f2   = (blk >> 3) & 7;
    const int heg  = (blk >> 6) & 3;
    const int bb   = blk >> 8;
    const int fold = f1*8 + f2;

    const float* xb = x + (size_t)bb*96*4096 + (size_t)(f1*8)*64 + f2*8;

    // wave-uniform W/bias row base: wave holds 32 channels, lanes span px
    const float* wrow = (wid < 2) ? (Wf + (size_t)(heg*64 + wid*32)*96)
                                  : (Wv + (size_t)(heg*64 + (wid-2)*32)*96);
    const float* brow = (wid < 2) ? (bf + heg*64 + wid*32)
                                  : (bv + heg*64 + (wid-2)*32);

    float acc[32];
    #pragma unroll
    for (int c = 0; c < 32; ++c) acc[c] = brow[c];   // uniform s_load + bcast

    // staging decode: 2 float4/thread per 32k chunk.
    // fl=i*256+t: kl=fl>>4 (k), sg=fl&15 -> global row kl, px (sg>>1)*8+(sg&1)*4
    // LDS transposed: xch[px*33 + kl]  (banks (px+kl)%32: 2-way = free)
    int xoff[2], xbs[2];
    #pragma unroll
    for (int i = 0; i < 2; ++i) {
        int fl = i*256 + t;
        int kl = fl >> 4, sg = fl & 15;
        xoff[i] = kl*4096 + (sg >> 1)*64 + (sg & 1)*4;
        xbs[i]  = ((sg >> 1)*8 + (sg & 1)*4)*33 + kl;
    }

    float4 pxr0 = *(const float4*)(xb + xoff[0]);
    float4 pxr1 = *(const float4*)(xb + xoff[1]);
    xch[xbs[0]] = pxr0.x; xch[xbs[0]+33] = pxr0.y;
    xch[xbs[0]+66] = pxr0.z; xch[xbs[0]+99] = pxr0.w;
    xch[xbs[1]] = pxr1.x; xch[xbs[1]+33] = pxr1.y;
    xch[xbs[1]+66] = pxr1.z; xch[xbs[1]+99] = pxr1.w;
    __syncthreads();

    const int lx = lane*33;
    for (int kc = 0; ; ) {
        if (kc < 64) {                  // prefetch next chunk into regs
            pxr0 = *(const float4*)(xb + (kc+32)*4096 + xoff[0]);
            pxr1 = *(const float4*)(xb + (kc+32)*4096 + xoff[1]);
        }
        // 32 k: per kg: 8 ds_read_b32 (x), W from SGPRs (s_load_dwordx8)
        #pragma unroll
        for (int kg = 0; kg < 4; ++kg) {
            float xv[8];
            #pragma unroll
            for (int j = 0; j < 8; ++j) xv[j] = xch[lx + kg*8 + j];
            #pragma unroll
            for (int c = 0; c < 32; ++c) {
                const float* wp = wrow + c*96 + (kc + kg*8);   // uniform
                #pragma unroll
                for (int j = 0; j < 8; ++j)
                    acc[c] = fmaf(wp[j], xv[j], acc[c]);
            }
        }
        if (kc == 64) break;
        __syncthreads();                // chunk consumed
        xch[xbs[0]] = pxr0.x; xch[xbs[0]+33] = pxr0.y;
        xch[xbs[0]+66] = pxr0.z; xch[xbs[0]+99] = pxr0.w;
        xch[xbs[1]] = pxr1.x; xch[xbs[1]+33] = pxr1.y;
        xch[xbs[1]+66] = pxr1.z; xch[xbs[1]+99] = pxr1.w;
        __syncthreads();                // next chunk ready
        kc += 32;
    }

    // ---- cluster: f-head fully in wave 0/1 regs, v-head in wave 2/3 ----
    const float alpha = salpha[0], beta = sbeta[0];
    // pooling: region of lane n: m = ((n>>5)&1)*2 + ((n>>2)&1); max over
    // n xor {1,2,8,16} (h&3 bits 0-1, r&3 bits 3-4). Max is order-exact.
    const int m = ((lane >> 5) & 1)*2 + ((lane >> 2) & 1);
    const bool rep = (lane & 27) == 0;  // r&3==0 && h&3==0
    #pragma unroll
    for (int c = 0; c < 32; ++c) {
        float rm = acc[c];
        rm = dpp_max<0xB1>(rm);                  // quad_perm [1,0,3,2] xor1
        rm = dpp_max<0x4E>(rm);                  // quad_perm [2,3,0,1] xor2
        rm = dpp_max<0x128>(rm);                 // row_ror:8 -> xor8
        rm = fmaxf(rm, __shfl_xor(rm, 16));      // xor16
        if (rep) { if (wid < 2) cfs[he][c*4 + m] = rm; else cvs[he][c*4 + m] = rm; }
    }

    if (wid < 2) {
        // sims: f in regs, centers via uniform b128 broadcast reads
        float d0=0,d1=0,d2=0,d3=0,pn=0,cn0=0,cn1=0,cn2=0,cn3=0;
        #pragma unroll
        for (int c = 0; c < 32; ++c) {
            float4 cf = *(const float4*)&cfs[he][c*4];
            float fv = acc[c];
            d0 = fmaf(cf.x, fv, d0); d1 = fmaf(cf.y, fv, d1);
            d2 = fmaf(cf.z, fv, d2); d3 = fmaf(cf.w, fv, d3);
            pn = fmaf(fv, fv, pn);
            cn0 = fmaf(cf.x, cf.x, cn0); cn1 = fmaf(cf.y, cf.y, cn1);
            cn2 = fmaf(cf.z, cf.z, cn2); cn3 = fmaf(cf.w, cf.w, cn3);
        }
        float ip = 1.f / fmaxf(sqrtf(pn), 1e-12f);
        float z0 = beta + alpha*(d0*(1.f/fmaxf(sqrtf(cn0),1e-12f))*ip);
        float z1 = beta + alpha*(d1*(1.f/fmaxf(sqrtf(cn1),1e-12f))*ip);
        float z2 = beta + alpha*(d2*(1.f/fmaxf(sqrtf(cn2),1e-12f))*ip);
        float z3 = beta + alpha*(d3*(1.f/fmaxf(sqrtf(cn3),1e-12f))*ip);
        float s0 = 1.f/(1.f + expf(-z0));
        float s1 = 1.f/(1.f + expf(-z1));
        float s2 = 1.f/(1.f + expf(-z2));
        float s3 = 1.f/(1.f + expf(-z3));
        int bi = 0; float bvv = s0;   // first-max tie-break
        if (s1 > bvv) { bvv = s1; bi = 1; }
        if (s2 > bvv) { bvv = s2; bi = 2; }
        if (s3 > bvv) { bvv = s3; bi = 3; }
        int cnt0 = __popcll(__ballot(bi == 0));
        int cnt1 = __popcll(__ballot(bi == 1));
        int cnt2 = __popcll(__ballot(bi == 2));
        int cnt3 = __popcll(__ballot(bi == 3));
        swb[he][lane]       = (bi==0) ? bvv : 0.f;
        swb[he][64 + lane]  = (bi==1) ? bvv : 0.f;
        swb[he][128 + lane] = (bi==2) ? bvv : 0.f;
        swb[he][192 + lane] = (bi==3) ? bvv : 0.f;
        bib[he][lane] = make_float2(bvv, (float)bi);
        if (lane == 0) {
            cnts[he][0] = (float)cnt0; cnts[he][1] = (float)cnt1;
            cnts[he][2] = (float)cnt2; cnts[he][3] = (float)cnt3;
        }
    } else {
        // v dump [n][33c] (banks (n+c)%32, conflict-free)
        #pragma unroll
        for (int c = 0; c < 32; ++c) vd[he][lane*33 + c] = acc[c];
    }
    __syncthreads();

    if (wid >= 2) {
        // agg: lane -> (m = it*2 + lane>>5, c = lane&31)
        const int cI = lane & 31;
        #pragma unroll
        for (int it = 0; it < 2; ++it) {
            int mm = it*2 + (lane >> 5);
            float s = 0.f;
            #pragma unroll 8
            for (int n2 = 0; n2 < 64; ++n2)
                s = fmaf(vd[he][n2*33 + cI], swb[he][mm*64 + n2], s);
            aggs[he][mm*33 + cI] = (s + cvs[he][cI*4 + mm]) / (cnts[he][mm] + 1.f);
        }
        float2 b2 = bib[he][lane];
        float bvv = b2.x; int bi = (int)b2.y;
        const int e32 = (heg*2 + he)*32;
        const size_t obase = (size_t)bb*4096 + (size_t)fold*64 + lane;
        #pragma unroll 4
        for (int c = 0; c < 32; ++c)
            disp[(size_t)(e32 + c)*65536 + obase] = aggs[he][bi*33 + c] * bvv;
    }
}

// K2: C[96][p''] = Wp[96][256] @ disp[256][p''] + bp.
// Wave = 24 oc (W via s_load, wave-uniform, k-contiguous), lanes = 64 px.
// x: 1 ds_read_b32/k from [64px][33]. 1024 blocks (bb,fold), blk&7 = f1 =
// K1 writer's XCD.
__global__ __launch_bounds__(TPB, 4)
void cc_proj(const float* __restrict__ disp, const float* __restrict__ Wp,
             const float* __restrict__ bp, float* __restrict__ out)
{
    __shared__ __align__(16) float xch[64*33];
    const int t    = threadIdx.x;
    const int lane = t & 63;
    const int wid  = __builtin_amdgcn_readfirstlane(t >> 6);  // oc-block
    const int blk  = blockIdx.x;       // 0..1023
    const int f1   = blk & 7;
    const int f2   = (blk >> 3) & 7;
    const int bb   = blk >> 6;
    const int fold = f1*8 + f2;
    const int pxbase = bb*4096 + fold*64;

    const float* wrow = Wp + (size_t)(wid*24)*256;     // uniform
    float acc[24];
    #pragma unroll
    for (int o = 0; o < 24; ++o) acc[o] = bp[wid*24 + o];

    // staging: 2 float4/thread per 32k chunk; transposed to xch[px*33+k]
    int xoff[2], xbs[2];
    #pragma unroll
    for (int i = 0; i < 2; ++i) {
        int fl = i*256 + t;
        int kl = fl >> 4, sg = fl & 15;
        xoff[i] = kl*65536 + pxbase + sg*4;
        xbs[i]  = (sg*4)*33 + kl;
    }

    float4 pxr0 = *(const float4*)(disp + xoff[0]);
    float4 pxr1 = *(const float4*)(disp + xoff[1]);
    xch[xbs[0]] = pxr0.x; xch[xbs[0]+33] = pxr0.y;
    xch[xbs[0]+66] = pxr0.z; xch[xbs[0]+99] = pxr0.w;
    xch[xbs[1]] = pxr1.x; xch[xbs[1]+33] = pxr1.y;
    xch[xbs[1]+66] = pxr1.z; xch[xbs[1]+99] = pxr1.w;
    __syncthreads();

    const int lx = lane*33;
    for (int kc = 0; ; ) {
        if (kc < 224) {
            pxr0 = *(const float4*)(disp + (size_t)(kc+32)*65536 + xoff[0] - (size_t)0);
            pxr1 = *(const float4*)(disp + (size_t)(kc+32)*65536 + xoff[1] - (size_t)0);
        }
        #pragma unroll
        for (int kg = 0; kg < 4; ++kg) {
            float xv[8];
            #pragma unroll
            for (int j = 0; j < 8; ++j) xv[j] = xch[lx + kg*8 + j];
            #pragma unroll
            for (int o = 0; o < 24; ++o) {
                const float* wp = wrow + o*256 + (kc + kg*8);  // uniform
                #pragma unroll
                for (int j = 0; j < 8; ++j)
                    acc[o] = fmaf(wp[j], xv[j], acc[o]);
            }
        }
        if (kc == 224) break;
        __syncthreads();
        xch[xbs[0]] = pxr0.x; xch[xbs[0]+33] = pxr0.y;
        xch[xbs[0]+66] = pxr0.z; xch[xbs[0]+99] = pxr0.w;
        xch[xbs[1]] = pxr1.x; xch[xbs[1]+33] = pxr1.y;
        xch[xbs[1]+66] = pxr1.z; xch[xbs[1]+99] = pxr1.w;
        __syncthreads();
        kc += 32;
    }

    // epilogue: lane = px n -> out[bb][oc][f1*8 + n>>3][f2*8 + (n&7)]
    const int r = lane >> 3, hh = lane & 7;
    const size_t ob = (size_t)bb*96*4096 + (size_t)(f1*8 + r)*64 + f2*8 + hh;
    #pragma unroll
    for (int o = 0; o < 24; ++o)
        out[ob + (size_t)(wid*24 + o)*4096] = acc[o];
}

extern "C" void kernel_launch(void* const* d_in, const int* in_sizes, int n_in,
                              void* d_out, int out_size, void* d_ws, size_t ws_size,
                              hipStream_t stream) {
    (void)in_sizes; (void)n_in; (void)out_size; (void)ws_size;
    float* disp = (float*)d_ws;   // 256*65536 floats = 64 MiB, layout [ch][p'']
    cc_main<<<dim3(4096), dim3(TPB), 0, stream>>>(
        (const float*)d_in[0],  // x
        (const float*)d_in[1],  // Wf
        (const float*)d_in[2],  // bf
        (const float*)d_in[3],  // Wv
        (const float*)d_in[4],  // bv
        (const float*)d_in[7],  // sim_alpha
        (const float*)d_in[8],  // sim_beta
        disp);
    cc_proj<<<dim3(1024), dim3(TPB), 0, stream>>>(
        disp,
        (const float*)d_in[5],  // Wp
        (const float*)d_in[6],  // bp
        (float*)d_out);
}

// Round 4
// 248.210 us; speedup vs baseline: 1.0963x; 1.0963x over previous
//
#include <hip/hip_runtime.h>
#include <math.h>

// ContextCluster, fp32, MI355X gfx950 — round 13.
// R12 failed at container level (no compile/validation error, no counters).
// Audit found no OOB/alignment/divergent-sync hazard in R12, but to separate
// infra-flake from GPU-fault this round de-risks: cc_main is the
// BYTE-IDENTICAL R10 kernel that passed at 127.7us; only cc_proj takes
// R12's high-certainty retile (8oc x 4px thread tile, 192 threads,
// instr/FMA 1.8 -> 1.3, LDS-instr/FMA 0.33 -> 0.09). The cc_main 2-fold
// restructure is deferred until counters confirm the platform is healthy.

#define TPB 256

__global__ __launch_bounds__(TPB, 4)
void cc_main(const float* __restrict__ x,
             const float* __restrict__ Wf, const float* __restrict__ bf,
             const float* __restrict__ Wv, const float* __restrict__ bv,
             const float* __restrict__ salpha, const float* __restrict__ sbeta,
             float* __restrict__ disp)
{
    // GEMM: Wt = smem[0..4096) [32k][128ch], Xt = smem[4096..6144) [32k][64px]
    // Cluster: fvbuf = smem[0..8320) [128ch][65]
    __shared__ __align__(16) float smem[8320];
    __shared__ float cfs[2][132], cvs[2][132], swb[2][256], aggs[2][132];
    __shared__ float2 bib[2][64];
    __shared__ float cnts[2][4];

    const int t    = threadIdx.x;
    const int lane = t & 63;
    const int wid  = __builtin_amdgcn_readfirstlane(t >> 6);  // 0..3
    const int tc   = t >> 4;          // 0..15: ch-group (8 ch)
    const int tp   = t & 15;          // px-group (4 consecutive px)
    const int blk  = blockIdx.x;
    // XCD-partitioned decode: XCD = blk&7 = f1 -> each XCD touches only its
    // own 3.1 MB x row-slice; heg (re-reader of same 24KB chunk) is 8 blocks
    // apart in XCD-local dispatch order -> L2-resident reuse.
    const int f1   = blk & 7;
    const int f2   = (blk >> 3) & 7;
    const int heg  = (blk >> 6) & 3;  // head-pair 0..3
    const int bb   = blk >> 8;        // batch 0..15
    const int fold = f1*8 + f2;

    const float* xb = x + (size_t)bb*96*4096 + (size_t)(f1*8)*64 + f2*8;

    // ---- accumulators (8 ch x 4 px), bias-init ----
    float acc[8][4];
    {
        const float* bsrc = (tc < 8) ? (bf + heg*64 + tc*8)
                                     : (bv + heg*64 + (tc-8)*8);
        float4 b0 = *(const float4*)bsrc;
        float4 b1 = *(const float4*)(bsrc + 4);
        #pragma unroll
        for (int i = 0; i < 4; ++i) {
            acc[0][i]=b0.x; acc[1][i]=b0.y; acc[2][i]=b0.z; acc[3][i]=b0.w;
            acc[4][i]=b1.x; acc[5][i]=b1.y; acc[6][i]=b1.z; acc[7][i]=b1.w;
        }
    }

    // ---- staging decode (t-constant) ----
    // X: 512 float4/chunk, 2/thread
    int xoff[2], xdst[2];
    #pragma unroll
    for (int i = 0; i < 2; ++i) {
        int fl = i*256 + t;
        int kl = fl >> 4, sg = fl & 15;
        xoff[i] = kl*4096 + (sg >> 1)*64 + (sg & 1)*4;
        xdst[i] = 4096 + kl*64 + sg*4;
    }
    // W: 1024 float4/chunk, 4/thread; rr = fl&127 -> 64 consecutive rr per
    // store instr -> 2 lanes/bank (conflict-free). kq wave-uniform.
    int wdst[4];
    const float* wptr[4];
    #pragma unroll
    for (int i = 0; i < 4; ++i) {
        int fl = i*256 + t;
        int rr = fl & 127, kq = fl >> 7;
        wptr[i] = ((rr < 64) ? (Wf + (size_t)(heg*64 + rr)*96)
                             : (Wv + (size_t)(heg*64 + rr - 64)*96)) + kq*4;
        wdst[i] = (kq*4)*128 + rr;
    }

    float4 pxr[2], pwr[4];
    #pragma unroll
    for (int i = 0; i < 2; ++i) pxr[i] = *(const float4*)(xb + xoff[i]);
    #pragma unroll
    for (int i = 0; i < 4; ++i) pwr[i] = *(const float4*)(wptr[i]);
    #pragma unroll
    for (int i = 0; i < 2; ++i) *(float4*)&smem[xdst[i]] = pxr[i];
    #pragma unroll
    for (int i = 0; i < 4; ++i) {
        smem[wdst[i]      ] = pwr[i].x;
        smem[wdst[i] + 128] = pwr[i].y;
        smem[wdst[i] + 256] = pwr[i].z;
        smem[wdst[i] + 384] = pwr[i].w;
    }
    __syncthreads();                  // chunk0 ready

    for (int kc = 0; ; ) {
        if (kc < 64) {                // prefetch next chunk into regs
            #pragma unroll
            for (int i = 0; i < 2; ++i)
                pxr[i] = *(const float4*)(xb + (kc+32)*4096 + xoff[i]);
            #pragma unroll
            for (int i = 0; i < 4; ++i)
                pwr[i] = *(const float4*)(wptr[i] + kc + 32);
        }
        // ---- GEMM chunk: 32 k, 32 FMA/thread/k, 3 LDS b128/thread/k ----
        #pragma unroll 4
        for (int k = 0; k < 32; ++k) {
            float4 wa  = *(const float4*)&smem[k*128 + tc*8];
            float4 wb4 = *(const float4*)&smem[k*128 + tc*8 + 4];
            float4 xq  = *(const float4*)&smem[4096 + k*64 + tp*4];
            float xv[4] = {xq.x, xq.y, xq.z, xq.w};
            #pragma unroll
            for (int i = 0; i < 4; ++i) {
                acc[0][i] = fmaf(wa.x,  xv[i], acc[0][i]);
                acc[1][i] = fmaf(wa.y,  xv[i], acc[1][i]);
                acc[2][i] = fmaf(wa.z,  xv[i], acc[2][i]);
                acc[3][i] = fmaf(wa.w,  xv[i], acc[3][i]);
                acc[4][i] = fmaf(wb4.x, xv[i], acc[4][i]);
                acc[5][i] = fmaf(wb4.y, xv[i], acc[5][i]);
                acc[6][i] = fmaf(wb4.z, xv[i], acc[6][i]);
                acc[7][i] = fmaf(wb4.w, xv[i], acc[7][i]);
            }
        }
        if (kc == 64) break;
        __syncthreads();              // chunk consumed
        #pragma unroll
        for (int i = 0; i < 2; ++i) *(float4*)&smem[xdst[i]] = pxr[i];
        #pragma unroll
        for (int i = 0; i < 4; ++i) {
            smem[wdst[i]      ] = pwr[i].x;
            smem[wdst[i] + 128] = pwr[i].y;
            smem[wdst[i] + 256] = pwr[i].z;
            smem[wdst[i] + 384] = pwr[i].w;
        }
        __syncthreads();              // next chunk ready
        kc += 32;
    }

    // ---- cluster: dump conv result, waves 0/1 handle heads he=wid ----
    const float alpha = salpha[0], beta = sbeta[0];
    __syncthreads();                  // GEMM reads of smem done
    #pragma unroll
    for (int j = 0; j < 8; ++j)
        #pragma unroll
        for (int i2 = 0; i2 < 4; ++i2)
            smem[(tc*8 + j)*65 + tp*4 + i2] = acc[j][i2];
    __syncthreads();

    if (wid < 2) {
        const int he = wid, slot = he;
        // pool: lane -> (m = lane>>4, c0 = (lane&15)*2), 2 centers each
        {
            int m = lane >> 4, c0 = (lane & 15)*2;
            int pw = m >> 1, ph = m & 1;
            #pragma unroll
            for (int cc = 0; cc < 2; ++cc) {
                int c = c0 + cc;
                float mf = -3.402823466e38f, mv = -3.402823466e38f;
                #pragma unroll
                for (int a = 0; a < 4; ++a)
                    #pragma unroll
                    for (int b2 = 0; b2 < 4; ++b2) {
                        int n = (pw*4 + a)*8 + ph*4 + b2;
                        mf = fmaxf(mf, smem[(he*32 + c)*65 + n]);
                        mv = fmaxf(mv, smem[(64 + he*32 + c)*65 + n]);
                    }
                cfs[slot][m*33 + c] = mf;
                cvs[slot][m*33 + c] = mv;
            }
        }
        // sims (lane = n)
        float d0=0,d1=0,d2=0,d3=0,pn=0,cn0=0,cn1=0,cn2=0,cn3=0;
        #pragma unroll 8
        for (int c = 0; c < 32; ++c) {
            float fv = smem[(he*32 + c)*65 + lane];
            float m0 = cfs[slot][c], m1 = cfs[slot][33+c];
            float m2 = cfs[slot][66+c], m3 = cfs[slot][99+c];
            d0 = fmaf(m0, fv, d0); d1 = fmaf(m1, fv, d1);
            d2 = fmaf(m2, fv, d2); d3 = fmaf(m3, fv, d3);
            pn = fmaf(fv, fv, pn);
            cn0 = fmaf(m0, m0, cn0); cn1 = fmaf(m1, m1, cn1);
            cn2 = fmaf(m2, m2, cn2); cn3 = fmaf(m3, m3, cn3);
        }
        float ip = 1.f / fmaxf(sqrtf(pn), 1e-12f);
        float z0 = beta + alpha*(d0*(1.f/fmaxf(sqrtf(cn0),1e-12f))*ip);
        float z1 = beta + alpha*(d1*(1.f/fmaxf(sqrtf(cn1),1e-12f))*ip);
        float z2 = beta + alpha*(d2*(1.f/fmaxf(sqrtf(cn2),1e-12f))*ip);
        float z3 = beta + alpha*(d3*(1.f/fmaxf(sqrtf(cn3),1e-12f))*ip);
        float s0 = 1.f/(1.f + expf(-z0));
        float s1 = 1.f/(1.f + expf(-z1));
        float s2 = 1.f/(1.f + expf(-z2));
        float s3 = 1.f/(1.f + expf(-z3));
        int bi = 0; float bvv = s0;   // first-max tie-break
        if (s1 > bvv) { bvv = s1; bi = 1; }
        if (s2 > bvv) { bvv = s2; bi = 2; }
        if (s3 > bvv) { bvv = s3; bi = 3; }
        int cnt0 = __popcll(__ballot(bi == 0));
        int cnt1 = __popcll(__ballot(bi == 1));
        int cnt2 = __popcll(__ballot(bi == 2));
        int cnt3 = __popcll(__ballot(bi == 3));
        swb[slot][lane]       = (bi==0) ? bvv : 0.f;
        swb[slot][64 + lane]  = (bi==1) ? bvv : 0.f;
        swb[slot][128 + lane] = (bi==2) ? bvv : 0.f;
        swb[slot][192 + lane] = (bi==3) ? bvv : 0.f;
        bib[slot][lane] = make_float2(bvv, (float)bi);
        if (lane == 0) {
            cnts[slot][0] = (float)cnt0; cnts[slot][1] = (float)cnt1;
            cnts[slot][2] = (float)cnt2; cnts[slot][3] = (float)cnt3;
        }
    }
    __syncthreads();

    if (wid >= 2) {
        const int he = wid - 2, slot = he;
        // agg: 2 iters, lane -> (m = it*2 + lane>>5, c = lane&31)
        const int cI = lane & 31;
        #pragma unroll
        for (int it = 0; it < 2; ++it) {
            int mm = it*2 + (lane >> 5);
            float s = 0.f;
            #pragma unroll 8
            for (int n2 = 0; n2 < 64; ++n2)
                s = fmaf(smem[(64 + he*32 + cI)*65 + n2],
                         swb[slot][mm*64 + n2], s);
            aggs[slot][mm*33 + cI] = (s + cvs[slot][mm*33 + cI])
                                   / (cnts[slot][mm] + 1.f);
        }
        float2 b2 = bib[slot][lane];
        float bvv = b2.x; int bi = (int)b2.y;
        const int e32 = (heg*2 + he)*32;
        const size_t obase = (size_t)bb*4096 + (size_t)fold*64 + lane;
        #pragma unroll 4
        for (int c = 0; c < 32; ++c)
            disp[(size_t)(e32 + c)*65536 + obase] = aggs[slot][bi*33 + c] * bvv;
    }
}

// K2: C[96][p''] = Wp[96][256] @ disp[256][p''] + bp.
// 1024 blocks (bb, fold), 192 threads, tile 96oc x 64px, thread 8oc x 4px.
// blk&7 = f1 = K1 writer's XCD.
__global__ __launch_bounds__(192, 3)
void cc_proj(const float* __restrict__ disp, const float* __restrict__ Wp,
             const float* __restrict__ bp, float* __restrict__ out)
{
    __shared__ __align__(16) float wch[3200];    // [32k][100] (96 oc, pad)
    __shared__ __align__(16) float xch[2048];    // [32k][64px]
    const int t   = threadIdx.x;
    const int cg  = t >> 4;           // 0..11: oc-group (8 oc)
    const int pg  = t & 15;           // 0..15: px-group (4 consecutive px)
    const int blk = blockIdx.x;       // 0..1023
    const int f1  = blk & 7;
    const int f2  = (blk >> 3) & 7;
    const int bb  = blk >> 6;
    const int pxbase = bb*4096 + (f1*8 + f2)*64;

    float acc[8][4];
    {
        const float* bsrc = bp + cg*8;
        float4 b0 = *(const float4*)bsrc, b1 = *(const float4*)(bsrc + 4);
        float bj[8] = {b0.x,b0.y,b0.z,b0.w,b1.x,b1.y,b1.z,b1.w};
        #pragma unroll
        for (int j = 0; j < 8; ++j)
            #pragma unroll
            for (int i = 0; i < 4; ++i) acc[j][i] = bj[j];
    }

    // staging decode. W: 768 f4/chunk, 4/thread; rr consecutive -> 2-way.
    int wdst[4]; int woff[4];
    #pragma unroll
    for (int i = 0; i < 4; ++i) {
        int fl = i*192 + t;           // 0..767
        int rr = fl % 96, kq = fl / 96;   // kq 0..7
        woff[i] = rr*256 + kq*4;
        wdst[i] = (kq*4)*100 + rr;
    }
    // X: 512 f4/chunk; 2/thread + 1 extra for t<128
    int xdst[3]; int xoff[3];
    #pragma unroll
    for (int i = 0; i < 3; ++i) {
        int fl = i*192 + t;
        int kl = fl >> 4, p4 = (fl & 15)*4;
        xoff[i] = kl*65536 + pxbase + p4;
        xdst[i] = kl*64 + p4;
    }
    const bool x3 = (t < 128);

    float4 pwr[4], pxr[3];
    #pragma unroll
    for (int i = 0; i < 4; ++i) pwr[i] = *(const float4*)(Wp + woff[i]);
    pxr[0] = *(const float4*)(disp + xoff[0]);
    pxr[1] = *(const float4*)(disp + xoff[1]);
    if (x3) pxr[2] = *(const float4*)(disp + xoff[2]);
    #pragma unroll
    for (int i = 0; i < 4; ++i) {
        wch[wdst[i]      ] = pwr[i].x; wch[wdst[i] + 100] = pwr[i].y;
        wch[wdst[i] + 200] = pwr[i].z; wch[wdst[i] + 300] = pwr[i].w;
    }
    *(float4*)&xch[xdst[0]] = pxr[0];
    *(float4*)&xch[xdst[1]] = pxr[1];
    if (x3) *(float4*)&xch[xdst[2]] = pxr[2];
    __syncthreads();

    for (int kc = 0; ; ) {
        if (kc < 224) {
            #pragma unroll
            for (int i = 0; i < 4; ++i)
                pwr[i] = *(const float4*)(Wp + woff[i] + kc + 32);
            pxr[0] = *(const float4*)(disp + xoff[0] + (size_t)(kc+32)*65536);
            pxr[1] = *(const float4*)(disp + xoff[1] + (size_t)(kc+32)*65536);
            if (x3) pxr[2] = *(const float4*)(disp + xoff[2] + (size_t)(kc+32)*65536);
        }
        #pragma unroll 4
        for (int k = 0; k < 32; ++k) {
            float4 wa = *(const float4*)&wch[k*100 + cg*8];
            float4 wb = *(const float4*)&wch[k*100 + cg*8 + 4];
            float4 xq = *(const float4*)&xch[k*64 + pg*4];
            float wv[8] = {wa.x,wa.y,wa.z,wa.w,wb.x,wb.y,wb.z,wb.w};
            float xv[4] = {xq.x,xq.y,xq.z,xq.w};
            #pragma unroll
            for (int j = 0; j < 8; ++j)
                #pragma unroll
                for (int i = 0; i < 4; ++i)
                    acc[j][i] = fmaf(wv[j], xv[i], acc[j][i]);
        }
        if (kc == 224) break;
        __syncthreads();
        #pragma unroll
        for (int i = 0; i < 4; ++i) {
            wch[wdst[i]      ] = pwr[i].x; wch[wdst[i] + 100] = pwr[i].y;
            wch[wdst[i] + 200] = pwr[i].z; wch[wdst[i] + 300] = pwr[i].w;
        }
        *(float4*)&xch[xdst[0]] = pxr[0];
        *(float4*)&xch[xdst[1]] = pxr[1];
        if (x3) *(float4*)&xch[xdst[2]] = pxr[2];
        __syncthreads();
        kc += 32;
    }

    // epilogue: n = pg*4+i -> out[bb][oc][f1*8 + (pg>>1)][f2*8 + (pg&1)*4 + i]
    const size_t ob = (size_t)bb*96*4096 + (size_t)(f1*8 + (pg >> 1))*64
                    + f2*8 + (pg & 1)*4;
    #pragma unroll
    for (int j = 0; j < 8; ++j) {
        float4 st = make_float4(acc[j][0], acc[j][1], acc[j][2], acc[j][3]);
        *(float4*)&out[ob + (size_t)(cg*8 + j)*4096] = st;
    }
}

extern "C" void kernel_launch(void* const* d_in, const int* in_sizes, int n_in,
                              void* d_out, int out_size, void* d_ws, size_t ws_size,
                              hipStream_t stream) {
    (void)in_sizes; (void)n_in; (void)out_size; (void)ws_size;
    float* disp = (float*)d_ws;   // 256*65536 floats = 64 MiB, layout [ch][p'']
    cc_main<<<dim3(4096), dim3(TPB), 0, stream>>>(
        (const float*)d_in[0],  // x
        (const float*)d_in[1],  // Wf
        (const float*)d_in[2],  // bf
        (const float*)d_in[3],  // Wv
        (const float*)d_in[4],  // bv
        (const float*)d_in[7],  // sim_alpha
        (const float*)d_in[8],  // sim_beta
        disp);
    cc_proj<<<dim3(1024), dim3(192), 0, stream>>>(
        disp,
        (const float*)d_in[5],  // Wp
        (const float*)d_in[6],  // bp
        (float*)d_out);
}

// Round 5
// 244.402 us; speedup vs baseline: 1.1133x; 1.0156x over previous
//
#include <hip/hip_runtime.h>
#include <math.h>

// ContextCluster, fp32, MI355X gfx950 — round 14.
// R13 negative result: cc_proj retile (LDS instrs -2.6x) changed nothing ->
// cc_proj is memory-LATENCY-bound on disp[ch][p''] reads: 256B segments at
// 256KB stride, 64KB footprint scattered over 64MiB, ~0.8 TB/s effective.
// R14: disp becomes TILED [1024 tiles (bb,fold)][256 ch][64 px].
//  - cc_proj: each block reads ONE contiguous 64KB tile (8KB per chunk,
//    identity LDS mapping) -> streaming, page-local, same-XCD producer.
//  - cc_main: block writes 64 contiguous ch-rows of its tile (same 256B
//    per-instr coalescing, no more 256KB-stride spray) -> less write amp.
// Compute structure of both kernels byte-identical to R13 (which passed);
// only disp address arithmetic changed -> bit-identical output.

#define TPB 256

__global__ __launch_bounds__(TPB, 4)
void cc_main(const float* __restrict__ x,
             const float* __restrict__ Wf, const float* __restrict__ bf,
             const float* __restrict__ Wv, const float* __restrict__ bv,
             const float* __restrict__ salpha, const float* __restrict__ sbeta,
             float* __restrict__ disp)
{
    // GEMM: Wt = smem[0..4096) [32k][128ch], Xt = smem[4096..6144) [32k][64px]
    // Cluster: fvbuf = smem[0..8320) [128ch][65]
    __shared__ __align__(16) float smem[8320];
    __shared__ float cfs[2][132], cvs[2][132], swb[2][256], aggs[2][132];
    __shared__ float2 bib[2][64];
    __shared__ float cnts[2][4];

    const int t    = threadIdx.x;
    const int lane = t & 63;
    const int wid  = __builtin_amdgcn_readfirstlane(t >> 6);  // 0..3
    const int tc   = t >> 4;          // 0..15: ch-group (8 ch)
    const int tp   = t & 15;          // px-group (4 consecutive px)
    const int blk  = blockIdx.x;
    // XCD-partitioned decode: XCD = blk&7 = f1 -> each XCD touches only its
    // own 3.1 MB x row-slice; heg (re-reader of same 24KB chunk) is 8 blocks
    // apart in XCD-local dispatch order -> L2-resident reuse.
    const int f1   = blk & 7;
    const int f2   = (blk >> 3) & 7;
    const int heg  = (blk >> 6) & 3;  // head-pair 0..3
    const int bb   = blk >> 8;        // batch 0..15
    const int fold = f1*8 + f2;

    const float* xb = x + (size_t)bb*96*4096 + (size_t)(f1*8)*64 + f2*8;

    // ---- accumulators (8 ch x 4 px), bias-init ----
    float acc[8][4];
    {
        const float* bsrc = (tc < 8) ? (bf + heg*64 + tc*8)
                                     : (bv + heg*64 + (tc-8)*8);
        float4 b0 = *(const float4*)bsrc;
        float4 b1 = *(const float4*)(bsrc + 4);
        #pragma unroll
        for (int i = 0; i < 4; ++i) {
            acc[0][i]=b0.x; acc[1][i]=b0.y; acc[2][i]=b0.z; acc[3][i]=b0.w;
            acc[4][i]=b1.x; acc[5][i]=b1.y; acc[6][i]=b1.z; acc[7][i]=b1.w;
        }
    }

    // ---- staging decode (t-constant) ----
    // X: 512 float4/chunk, 2/thread
    int xoff[2], xdst[2];
    #pragma unroll
    for (int i = 0; i < 2; ++i) {
        int fl = i*256 + t;
        int kl = fl >> 4, sg = fl & 15;
        xoff[i] = kl*4096 + (sg >> 1)*64 + (sg & 1)*4;
        xdst[i] = 4096 + kl*64 + sg*4;
    }
    // W: 1024 float4/chunk, 4/thread; rr = fl&127 -> 64 consecutive rr per
    // store instr -> 2 lanes/bank (conflict-free). kq wave-uniform.
    int wdst[4];
    const float* wptr[4];
    #pragma unroll
    for (int i = 0; i < 4; ++i) {
        int fl = i*256 + t;
        int rr = fl & 127, kq = fl >> 7;
        wptr[i] = ((rr < 64) ? (Wf + (size_t)(heg*64 + rr)*96)
                             : (Wv + (size_t)(heg*64 + rr - 64)*96)) + kq*4;
        wdst[i] = (kq*4)*128 + rr;
    }

    float4 pxr[2], pwr[4];
    #pragma unroll
    for (int i = 0; i < 2; ++i) pxr[i] = *(const float4*)(xb + xoff[i]);
    #pragma unroll
    for (int i = 0; i < 4; ++i) pwr[i] = *(const float4*)(wptr[i]);
    #pragma unroll
    for (int i = 0; i < 2; ++i) *(float4*)&smem[xdst[i]] = pxr[i];
    #pragma unroll
    for (int i = 0; i < 4; ++i) {
        smem[wdst[i]      ] = pwr[i].x;
        smem[wdst[i] + 128] = pwr[i].y;
        smem[wdst[i] + 256] = pwr[i].z;
        smem[wdst[i] + 384] = pwr[i].w;
    }
    __syncthreads();                  // chunk0 ready

    for (int kc = 0; ; ) {
        if (kc < 64) {                // prefetch next chunk into regs
            #pragma unroll
            for (int i = 0; i < 2; ++i)
                pxr[i] = *(const float4*)(xb + (kc+32)*4096 + xoff[i]);
            #pragma unroll
            for (int i = 0; i < 4; ++i)
                pwr[i] = *(const float4*)(wptr[i] + kc + 32);
        }
        // ---- GEMM chunk: 32 k, 32 FMA/thread/k, 3 LDS b128/thread/k ----
        #pragma unroll 4
        for (int k = 0; k < 32; ++k) {
            float4 wa  = *(const float4*)&smem[k*128 + tc*8];
            float4 wb4 = *(const float4*)&smem[k*128 + tc*8 + 4];
            float4 xq  = *(const float4*)&smem[4096 + k*64 + tp*4];
            float xv[4] = {xq.x, xq.y, xq.z, xq.w};
            #pragma unroll
            for (int i = 0; i < 4; ++i) {
                acc[0][i] = fmaf(wa.x,  xv[i], acc[0][i]);
                acc[1][i] = fmaf(wa.y,  xv[i], acc[1][i]);
                acc[2][i] = fmaf(wa.z,  xv[i], acc[2][i]);
                acc[3][i] = fmaf(wa.w,  xv[i], acc[3][i]);
                acc[4][i] = fmaf(wb4.x, xv[i], acc[4][i]);
                acc[5][i] = fmaf(wb4.y, xv[i], acc[5][i]);
                acc[6][i] = fmaf(wb4.z, xv[i], acc[6][i]);
                acc[7][i] = fmaf(wb4.w, xv[i], acc[7][i]);
            }
        }
        if (kc == 64) break;
        __syncthreads();              // chunk consumed
        #pragma unroll
        for (int i = 0; i < 2; ++i) *(float4*)&smem[xdst[i]] = pxr[i];
        #pragma unroll
        for (int i = 0; i < 4; ++i) {
            smem[wdst[i]      ] = pwr[i].x;
            smem[wdst[i] + 128] = pwr[i].y;
            smem[wdst[i] + 256] = pwr[i].z;
            smem[wdst[i] + 384] = pwr[i].w;
        }
        __syncthreads();              // next chunk ready
        kc += 32;
    }

    // ---- cluster: dump conv result, waves 0/1 handle heads he=wid ----
    const float alpha = salpha[0], beta = sbeta[0];
    __syncthreads();                  // GEMM reads of smem done
    #pragma unroll
    for (int j = 0; j < 8; ++j)
        #pragma unroll
        for (int i2 = 0; i2 < 4; ++i2)
            smem[(tc*8 + j)*65 + tp*4 + i2] = acc[j][i2];
    __syncthreads();

    if (wid < 2) {
        const int he = wid, slot = he;
        // pool: lane -> (m = lane>>4, c0 = (lane&15)*2), 2 centers each
        {
            int m = lane >> 4, c0 = (lane & 15)*2;
            int pw = m >> 1, ph = m & 1;
            #pragma unroll
            for (int cc = 0; cc < 2; ++cc) {
                int c = c0 + cc;
                float mf = -3.402823466e38f, mv = -3.402823466e38f;
                #pragma unroll
                for (int a = 0; a < 4; ++a)
                    #pragma unroll
                    for (int b2 = 0; b2 < 4; ++b2) {
                        int n = (pw*4 + a)*8 + ph*4 + b2;
                        mf = fmaxf(mf, smem[(he*32 + c)*65 + n]);
                        mv = fmaxf(mv, smem[(64 + he*32 + c)*65 + n]);
                    }
                cfs[slot][m*33 + c] = mf;
                cvs[slot][m*33 + c] = mv;
            }
        }
        // sims (lane = n)
        float d0=0,d1=0,d2=0,d3=0,pn=0,cn0=0,cn1=0,cn2=0,cn3=0;
        #pragma unroll 8
        for (int c = 0; c < 32; ++c) {
            float fv = smem[(he*32 + c)*65 + lane];
            float m0 = cfs[slot][c], m1 = cfs[slot][33+c];
            float m2 = cfs[slot][66+c], m3 = cfs[slot][99+c];
            d0 = fmaf(m0, fv, d0); d1 = fmaf(m1, fv, d1);
            d2 = fmaf(m2, fv, d2); d3 = fmaf(m3, fv, d3);
            pn = fmaf(fv, fv, pn);
            cn0 = fmaf(m0, m0, cn0); cn1 = fmaf(m1, m1, cn1);
            cn2 = fmaf(m2, m2, cn2); cn3 = fmaf(m3, m3, cn3);
        }
        float ip = 1.f / fmaxf(sqrtf(pn), 1e-12f);
        float z0 = beta + alpha*(d0*(1.f/fmaxf(sqrtf(cn0),1e-12f))*ip);
        float z1 = beta + alpha*(d1*(1.f/fmaxf(sqrtf(cn1),1e-12f))*ip);
        float z2 = beta + alpha*(d2*(1.f/fmaxf(sqrtf(cn2),1e-12f))*ip);
        float z3 = beta + alpha*(d3*(1.f/fmaxf(sqrtf(cn3),1e-12f))*ip);
        float s0 = 1.f/(1.f + expf(-z0));
        float s1 = 1.f/(1.f + expf(-z1));
        float s2 = 1.f/(1.f + expf(-z2));
        float s3 = 1.f/(1.f + expf(-z3));
        int bi = 0; float bvv = s0;   // first-max tie-break
        if (s1 > bvv) { bvv = s1; bi = 1; }
        if (s2 > bvv) { bvv = s2; bi = 2; }
        if (s3 > bvv) { bvv = s3; bi = 3; }
        int cnt0 = __popcll(__ballot(bi == 0));
        int cnt1 = __popcll(__ballot(bi == 1));
        int cnt2 = __popcll(__ballot(bi == 2));
        int cnt3 = __popcll(__ballot(bi == 3));
        swb[slot][lane]       = (bi==0) ? bvv : 0.f;
        swb[slot][64 + lane]  = (bi==1) ? bvv : 0.f;
        swb[slot][128 + lane] = (bi==2) ? bvv : 0.f;
        swb[slot][192 + lane] = (bi==3) ? bvv : 0.f;
        bib[slot][lane] = make_float2(bvv, (float)bi);
        if (lane == 0) {
            cnts[slot][0] = (float)cnt0; cnts[slot][1] = (float)cnt1;
            cnts[slot][2] = (float)cnt2; cnts[slot][3] = (float)cnt3;
        }
    }
    __syncthreads();

    if (wid >= 2) {
        const int he = wid - 2, slot = he;
        // agg: 2 iters, lane -> (m = it*2 + lane>>5, c = lane&31)
        const int cI = lane & 31;
        #pragma unroll
        for (int it = 0; it < 2; ++it) {
            int mm = it*2 + (lane >> 5);
            float s = 0.f;
            #pragma unroll 8
            for (int n2 = 0; n2 < 64; ++n2)
                s = fmaf(smem[(64 + he*32 + cI)*65 + n2],
                         swb[slot][mm*64 + n2], s);
            aggs[slot][mm*33 + cI] = (s + cvs[slot][mm*33 + cI])
                                   / (cnts[slot][mm] + 1.f);
        }
        float2 b2 = bib[slot][lane];
        float bvv = b2.x; int bi = (int)b2.y;
        // TILED disp: tile (bb,fold) is contiguous [256 ch][64 px]
        const int e32 = (heg*2 + he)*32;
        const size_t tbase = ((size_t)(bb*64 + fold))*16384
                           + (size_t)e32*64 + lane;
        #pragma unroll 4
        for (int c = 0; c < 32; ++c)
            disp[tbase + (size_t)c*64] = aggs[slot][bi*33 + c] * bvv;
    }
}

// K2: C[96][px] = Wp[96][256] @ tile[256][64] + bp, per (bb,fold) tile.
// 1024 blocks, 192 threads, tile 96oc x 64px, thread 8oc x 4px.
// disp tile is CONTIGUOUS 64KB -> streaming reads, identity LDS mapping.
// blk&7 = f1 = K1 writer's XCD.
__global__ __launch_bounds__(192, 3)
void cc_proj(const float* __restrict__ disp, const float* __restrict__ Wp,
             const float* __restrict__ bp, float* __restrict__ out)
{
    __shared__ __align__(16) float wch[3200];    // [32k][100] (96 oc, pad)
    __shared__ __align__(16) float xch[2048];    // [32k][64px]
    const int t   = threadIdx.x;
    const int cg  = t >> 4;           // 0..11: oc-group (8 oc)
    const int pg  = t & 15;           // 0..15: px-group (4 consecutive px)
    const int blk = blockIdx.x;       // 0..1023
    const int f1  = blk & 7;
    const int f2  = (blk >> 3) & 7;
    const int bb  = blk >> 6;
    const float* tb = disp + ((size_t)(bb*64 + f1*8 + f2))*16384;

    float acc[8][4];
    {
        const float* bsrc = bp + cg*8;
        float4 b0 = *(const float4*)bsrc, b1 = *(const float4*)(bsrc + 4);
        float bj[8] = {b0.x,b0.y,b0.z,b0.w,b1.x,b1.y,b1.z,b1.w};
        #pragma unroll
        for (int j = 0; j < 8; ++j)
            #pragma unroll
            for (int i = 0; i < 4; ++i) acc[j][i] = bj[j];
    }

    // staging decode. W: 768 f4/chunk, 4/thread; rr consecutive -> 2-way.
    int wdst[4]; int woff[4];
    #pragma unroll
    for (int i = 0; i < 4; ++i) {
        int fl = i*192 + t;           // 0..767
        int rr = fl % 96, kq = fl / 96;   // kq 0..7
        woff[i] = rr*256 + kq*4;
        wdst[i] = (kq*4)*100 + rr;
    }
    // X: 512 f4/chunk = one contiguous 8KB tile slice; identity LDS map.
    // 2/thread + 1 extra for t<128
    int xoff[3];
    #pragma unroll
    for (int i = 0; i < 3; ++i) xoff[i] = (i*192 + t)*4;
    const bool x3 = (t < 128);

    float4 pwr[4], pxr[3];
    #pragma unroll
    for (int i = 0; i < 4; ++i) pwr[i] = *(const float4*)(Wp + woff[i]);
    pxr[0] = *(const float4*)(tb + xoff[0]);
    pxr[1] = *(const float4*)(tb + xoff[1]);
    if (x3) pxr[2] = *(const float4*)(tb + xoff[2]);
    #pragma unroll
    for (int i = 0; i < 4; ++i) {
        wch[wdst[i]      ] = pwr[i].x; wch[wdst[i] + 100] = pwr[i].y;
        wch[wdst[i] + 200] = pwr[i].z; wch[wdst[i] + 300] = pwr[i].w;
    }
    *(float4*)&xch[xoff[0]] = pxr[0];
    *(float4*)&xch[xoff[1]] = pxr[1];
    if (x3) *(float4*)&xch[xoff[2]] = pxr[2];
    __syncthreads();

    for (int kc = 0; ; ) {
        if (kc < 224) {
            #pragma unroll
            for (int i = 0; i < 4; ++i)
                pwr[i] = *(const float4*)(Wp + woff[i] + kc + 32);
            pxr[0] = *(const float4*)(tb + (kc+32)*64 + xoff[0]);
            pxr[1] = *(const float4*)(tb + (kc+32)*64 + xoff[1]);
            if (x3) pxr[2] = *(const float4*)(tb + (kc+32)*64 + xoff[2]);
        }
        #pragma unroll 4
        for (int k = 0; k < 32; ++k) {
            float4 wa = *(const float4*)&wch[k*100 + cg*8];
            float4 wb = *(const float4*)&wch[k*100 + cg*8 + 4];
            float4 xq = *(const float4*)&xch[k*64 + pg*4];
            float wv[8] = {wa.x,wa.y,wa.z,wa.w,wb.x,wb.y,wb.z,wb.w};
            float xv[4] = {xq.x,xq.y,xq.z,xq.w};
            #pragma unroll
            for (int j = 0; j < 8; ++j)
                #pragma unroll
                for (int i = 0; i < 4; ++i)
                    acc[j][i] = fmaf(wv[j], xv[i], acc[j][i]);
        }
        if (kc == 224) break;
        __syncthreads();
        #pragma unroll
        for (int i = 0; i < 4; ++i) {
            wch[wdst[i]      ] = pwr[i].x; wch[wdst[i] + 100] = pwr[i].y;
            wch[wdst[i] + 200] = pwr[i].z; wch[wdst[i] + 300] = pwr[i].w;
        }
        *(float4*)&xch[xoff[0]] = pxr[0];
        *(float4*)&xch[xoff[1]] = pxr[1];
        if (x3) *(float4*)&xch[xoff[2]] = pxr[2];
        __syncthreads();
        kc += 32;
    }

    // epilogue: n = pg*4+i -> out[bb][oc][f1*8 + (pg>>1)][f2*8 + (pg&1)*4 + i]
    const size_t ob = (size_t)bb*96*4096 + (size_t)(f1*8 + (pg >> 1))*64
                    + f2*8 + (pg & 1)*4;
    #pragma unroll
    for (int j = 0; j < 8; ++j) {
        float4 st = make_float4(acc[j][0], acc[j][1], acc[j][2], acc[j][3]);
        *(float4*)&out[ob + (size_t)(cg*8 + j)*4096] = st;
    }
}

extern "C" void kernel_launch(void* const* d_in, const int* in_sizes, int n_in,
                              void* d_out, int out_size, void* d_ws, size_t ws_size,
                              hipStream_t stream) {
    (void)in_sizes; (void)n_in; (void)out_size; (void)ws_size;
    float* disp = (float*)d_ws;   // 1024 tiles x [256 ch][64 px] = 64 MiB
    cc_main<<<dim3(4096), dim3(TPB), 0, stream>>>(
        (const float*)d_in[0],  // x
        (const float*)d_in[1],  // Wf
        (const float*)d_in[2],  // bf
        (const float*)d_in[3],  // Wv
        (const float*)d_in[4],  // bv
        (const float*)d_in[7],  // sim_alpha
        (const float*)d_in[8],  // sim_beta
        disp);
    cc_proj<<<dim3(1024), dim3(192), 0, stream>>>(
        disp,
        (const float*)d_in[5],  // Wp
        (const float*)d_in[6],  // bp
        (float*)d_out);
}

// Round 6
// 209.069 us; speedup vs baseline: 1.3015x; 1.1690x over previous
//
#include <hip/hip_runtime.h>
#include <math.h>

// ContextCluster, fp32, MI355X gfx950 — round 15.
// R13/R14 decisive pattern: four structurally different cc_proj variants
// (tiles, layouts, grids) ALL land at 119-126us vs a 20.5us FMA floor ->
// the 64MiB disp round-trip itself is the cost, not K2's code.
// R15 algebraic collapse: disp[ch][n] = aggs[he][bi_n][c]*bvv_n has rank 4
// per (tile,head). Projection factors through proj_he[oc][m] =
// sum_c Wp[oc][ch]*aggs[he][m][c] (tiny 96x4x32 GEMM, done INSIDE cc_main
// where aggs already sits in LDS; +~49KFLOP/block). Intermediate shrinks
// 64MiB -> 16MiB (per tile: 8x96x4 proj + 8x64 (bvv,bi)). K2 becomes a
// gather-FMA: out[oc][n] = bp[oc] + sum_he proj_he[oc][bi_n]*bvv_n.
// Regroups the final sum (error ~1e-6 << 9.77e-4 tol); conv GEMM, pool,
// sim, agg phases bit-identical to R14 (passed).

#define TPB 256

__global__ __launch_bounds__(TPB, 4)
void cc_main(const float* __restrict__ x,
             const float* __restrict__ Wf, const float* __restrict__ bf,
             const float* __restrict__ Wv, const float* __restrict__ bv,
             const float* __restrict__ Wp,
             const float* __restrict__ salpha, const float* __restrict__ sbeta,
             float* __restrict__ cd)
{
    // GEMM: Wt = smem[0..4096) [32k][128ch], Xt = smem[4096..6144) [32k][64px]
    // Cluster: fvbuf = smem[0..8320) [128ch][65]
    __shared__ __align__(16) float smem[8320];
    __shared__ float cfs[2][132], cvs[2][132], swb[2][256], aggs[2][132];
    __shared__ float2 bib[2][64];
    __shared__ float cnts[2][4];

    const int t    = threadIdx.x;
    const int lane = t & 63;
    const int wid  = __builtin_amdgcn_readfirstlane(t >> 6);  // 0..3
    const int tc   = t >> 4;          // 0..15: ch-group (8 ch)
    const int tp   = t & 15;          // px-group (4 consecutive px)
    const int blk  = blockIdx.x;
    // XCD-partitioned decode: XCD = blk&7 = f1 -> x slice L2-resident.
    const int f1   = blk & 7;
    const int f2   = (blk >> 3) & 7;
    const int heg  = (blk >> 6) & 3;  // head-pair 0..3
    const int bb   = blk >> 8;        // batch 0..15
    const int fold = f1*8 + f2;

    const float* xb = x + (size_t)bb*96*4096 + (size_t)(f1*8)*64 + f2*8;

    // ---- accumulators (8 ch x 4 px), bias-init ----
    float acc[8][4];
    {
        const float* bsrc = (tc < 8) ? (bf + heg*64 + tc*8)
                                     : (bv + heg*64 + (tc-8)*8);
        float4 b0 = *(const float4*)bsrc;
        float4 b1 = *(const float4*)(bsrc + 4);
        #pragma unroll
        for (int i = 0; i < 4; ++i) {
            acc[0][i]=b0.x; acc[1][i]=b0.y; acc[2][i]=b0.z; acc[3][i]=b0.w;
            acc[4][i]=b1.x; acc[5][i]=b1.y; acc[6][i]=b1.z; acc[7][i]=b1.w;
        }
    }

    // ---- staging decode (t-constant) ----
    // X: 512 float4/chunk, 2/thread
    int xoff[2], xdst[2];
    #pragma unroll
    for (int i = 0; i < 2; ++i) {
        int fl = i*256 + t;
        int kl = fl >> 4, sg = fl & 15;
        xoff[i] = kl*4096 + (sg >> 1)*64 + (sg & 1)*4;
        xdst[i] = 4096 + kl*64 + sg*4;
    }
    // W: 1024 float4/chunk, 4/thread; rr = fl&127 -> 64 consecutive rr per
    // store instr -> 2 lanes/bank (conflict-free). kq wave-uniform.
    int wdst[4];
    const float* wptr[4];
    #pragma unroll
    for (int i = 0; i < 4; ++i) {
        int fl = i*256 + t;
        int rr = fl & 127, kq = fl >> 7;
        wptr[i] = ((rr < 64) ? (Wf + (size_t)(heg*64 + rr)*96)
                             : (Wv + (size_t)(heg*64 + rr - 64)*96)) + kq*4;
        wdst[i] = (kq*4)*128 + rr;
    }

    float4 pxr[2], pwr[4];
    #pragma unroll
    for (int i = 0; i < 2; ++i) pxr[i] = *(const float4*)(xb + xoff[i]);
    #pragma unroll
    for (int i = 0; i < 4; ++i) pwr[i] = *(const float4*)(wptr[i]);
    #pragma unroll
    for (int i = 0; i < 2; ++i) *(float4*)&smem[xdst[i]] = pxr[i];
    #pragma unroll
    for (int i = 0; i < 4; ++i) {
        smem[wdst[i]      ] = pwr[i].x;
        smem[wdst[i] + 128] = pwr[i].y;
        smem[wdst[i] + 256] = pwr[i].z;
        smem[wdst[i] + 384] = pwr[i].w;
    }
    __syncthreads();                  // chunk0 ready

    for (int kc = 0; ; ) {
        if (kc < 64) {                // prefetch next chunk into regs
            #pragma unroll
            for (int i = 0; i < 2; ++i)
                pxr[i] = *(const float4*)(xb + (kc+32)*4096 + xoff[i]);
            #pragma unroll
            for (int i = 0; i < 4; ++i)
                pwr[i] = *(const float4*)(wptr[i] + kc + 32);
        }
        // ---- GEMM chunk: 32 k, 32 FMA/thread/k, 3 LDS b128/thread/k ----
        #pragma unroll 4
        for (int k = 0; k < 32; ++k) {
            float4 wa  = *(const float4*)&smem[k*128 + tc*8];
            float4 wb4 = *(const float4*)&smem[k*128 + tc*8 + 4];
            float4 xq  = *(const float4*)&smem[4096 + k*64 + tp*4];
            float xv[4] = {xq.x, xq.y, xq.z, xq.w};
            #pragma unroll
            for (int i = 0; i < 4; ++i) {
                acc[0][i] = fmaf(wa.x,  xv[i], acc[0][i]);
                acc[1][i] = fmaf(wa.y,  xv[i], acc[1][i]);
                acc[2][i] = fmaf(wa.z,  xv[i], acc[2][i]);
                acc[3][i] = fmaf(wa.w,  xv[i], acc[3][i]);
                acc[4][i] = fmaf(wb4.x, xv[i], acc[4][i]);
                acc[5][i] = fmaf(wb4.y, xv[i], acc[5][i]);
                acc[6][i] = fmaf(wb4.z, xv[i], acc[6][i]);
                acc[7][i] = fmaf(wb4.w, xv[i], acc[7][i]);
            }
        }
        if (kc == 64) break;
        __syncthreads();              // chunk consumed
        #pragma unroll
        for (int i = 0; i < 2; ++i) *(float4*)&smem[xdst[i]] = pxr[i];
        #pragma unroll
        for (int i = 0; i < 4; ++i) {
            smem[wdst[i]      ] = pwr[i].x;
            smem[wdst[i] + 128] = pwr[i].y;
            smem[wdst[i] + 256] = pwr[i].z;
            smem[wdst[i] + 384] = pwr[i].w;
        }
        __syncthreads();              // next chunk ready
        kc += 32;
    }

    // ---- cluster: dump conv result, waves 0/1 handle heads he=wid ----
    const float alpha = salpha[0], beta = sbeta[0];
    __syncthreads();                  // GEMM reads of smem done
    #pragma unroll
    for (int j = 0; j < 8; ++j)
        #pragma unroll
        for (int i2 = 0; i2 < 4; ++i2)
            smem[(tc*8 + j)*65 + tp*4 + i2] = acc[j][i2];
    __syncthreads();

    if (wid < 2) {
        const int he = wid, slot = he;
        // pool: lane -> (m = lane>>4, c0 = (lane&15)*2), 2 centers each
        {
            int m = lane >> 4, c0 = (lane & 15)*2;
            int pw = m >> 1, ph = m & 1;
            #pragma unroll
            for (int cc = 0; cc < 2; ++cc) {
                int c = c0 + cc;
                float mf = -3.402823466e38f, mv = -3.402823466e38f;
                #pragma unroll
                for (int a = 0; a < 4; ++a)
                    #pragma unroll
                    for (int b2 = 0; b2 < 4; ++b2) {
                        int n = (pw*4 + a)*8 + ph*4 + b2;
                        mf = fmaxf(mf, smem[(he*32 + c)*65 + n]);
                        mv = fmaxf(mv, smem[(64 + he*32 + c)*65 + n]);
                    }
                cfs[slot][m*33 + c] = mf;
                cvs[slot][m*33 + c] = mv;
            }
        }
        // sims (lane = n)
        float d0=0,d1=0,d2=0,d3=0,pn=0,cn0=0,cn1=0,cn2=0,cn3=0;
        #pragma unroll 8
        for (int c = 0; c < 32; ++c) {
            float fv = smem[(he*32 + c)*65 + lane];
            float m0 = cfs[slot][c], m1 = cfs[slot][33+c];
            float m2 = cfs[slot][66+c], m3 = cfs[slot][99+c];
            d0 = fmaf(m0, fv, d0); d1 = fmaf(m1, fv, d1);
            d2 = fmaf(m2, fv, d2); d3 = fmaf(m3, fv, d3);
            pn = fmaf(fv, fv, pn);
            cn0 = fmaf(m0, m0, cn0); cn1 = fmaf(m1, m1, cn1);
            cn2 = fmaf(m2, m2, cn2); cn3 = fmaf(m3, m3, cn3);
        }
        float ip = 1.f / fmaxf(sqrtf(pn), 1e-12f);
        float z0 = beta + alpha*(d0*(1.f/fmaxf(sqrtf(cn0),1e-12f))*ip);
        float z1 = beta + alpha*(d1*(1.f/fmaxf(sqrtf(cn1),1e-12f))*ip);
        float z2 = beta + alpha*(d2*(1.f/fmaxf(sqrtf(cn2),1e-12f))*ip);
        float z3 = beta + alpha*(d3*(1.f/fmaxf(sqrtf(cn3),1e-12f))*ip);
        float s0 = 1.f/(1.f + expf(-z0));
        float s1 = 1.f/(1.f + expf(-z1));
        float s2 = 1.f/(1.f + expf(-z2));
        float s3 = 1.f/(1.f + expf(-z3));
        int bi = 0; float bvv = s0;   // first-max tie-break
        if (s1 > bvv) { bvv = s1; bi = 1; }
        if (s2 > bvv) { bvv = s2; bi = 2; }
        if (s3 > bvv) { bvv = s3; bi = 3; }
        int cnt0 = __popcll(__ballot(bi == 0));
        int cnt1 = __popcll(__ballot(bi == 1));
        int cnt2 = __popcll(__ballot(bi == 2));
        int cnt3 = __popcll(__ballot(bi == 3));
        swb[slot][lane]       = (bi==0) ? bvv : 0.f;
        swb[slot][64 + lane]  = (bi==1) ? bvv : 0.f;
        swb[slot][128 + lane] = (bi==2) ? bvv : 0.f;
        swb[slot][192 + lane] = (bi==3) ? bvv : 0.f;
        bib[slot][lane] = make_float2(bvv, (float)bi);
        if (lane == 0) {
            cnts[slot][0] = (float)cnt0; cnts[slot][1] = (float)cnt1;
            cnts[slot][2] = (float)cnt2; cnts[slot][3] = (float)cnt3;
        }
    }
    __syncthreads();

    // cd tile base: per (bb,fold): [8 he][96 oc][4 m] proj @0,
    //               [8 he][64 n] (bvv,bi) pairs @3072. 4096 floats = 16KB.
    float* tb = cd + ((size_t)(bb*64 + fold))*4096;

    if (wid >= 2) {
        const int he = wid - 2, slot = he;
        // agg: 2 iters, lane -> (m = it*2 + lane>>5, c = lane&31)
        const int cI = lane & 31;
        #pragma unroll
        for (int it = 0; it < 2; ++it) {
            int mm = it*2 + (lane >> 5);
            float s = 0.f;
            #pragma unroll 8
            for (int n2 = 0; n2 < 64; ++n2)
                s = fmaf(smem[(64 + he*32 + cI)*65 + n2],
                         swb[slot][mm*64 + n2], s);
            aggs[slot][mm*33 + cI] = (s + cvs[slot][mm*33 + cI])
                                   / (cnts[slot][mm] + 1.f);
        }
        // sel write: (bvv, bi) per pixel
        float2 b2 = bib[slot][lane];
        *(float2*)&tb[3072 + (heg*2 + he)*128 + lane*2] = b2;
    }
    __syncthreads();                  // aggs complete for all waves

    // ---- proj: proj_he[oc][m] = sum_c Wp[oc][heg*64+he*32+c]*aggs[he][m][c]
    // 768 outputs, 3 per thread; he wave-uniform each iteration.
    #pragma unroll
    for (int it = 0; it < 3; ++it) {
        int idx = it*256 + t;
        int he  = (idx >= 384) ? 1 : 0;
        int rem = idx - he*384;
        int oc  = rem >> 2, m = rem & 3;
        const float* wp = Wp + (size_t)oc*256 + heg*64 + he*32;
        const float* ag = aggs[he] + m*33;
        float s = 0.f;
        #pragma unroll
        for (int c = 0; c < 32; ++c)
            s = fmaf(wp[c], ag[c], s);
        tb[(heg*2 + he)*384 + oc*4 + m] = s;
    }
}

// K2-lite: out[oc][n] = bp[oc] + sum_he proj_he[oc][bi_n]*bvv_n per tile.
// 1024 blocks (bb,fold), 256 threads; stage 16KB contiguous tile in LDS;
// wave = 24 oc, lane = px n. blk&7 = f1 = K1 writer's XCD.
__global__ __launch_bounds__(TPB, 8)
void cc_comb(const float* __restrict__ cd, const float* __restrict__ bp,
             float* __restrict__ out)
{
    __shared__ __align__(16) float ld[4096];   // proj @0, sel @3072
    const int t    = threadIdx.x;
    const int lane = t & 63;
    const int wid  = __builtin_amdgcn_readfirstlane(t >> 6);  // oc-block
    const int blk  = blockIdx.x;       // 0..1023
    const int f1   = blk & 7;
    const int f2   = (blk >> 3) & 7;
    const int bb   = blk >> 6;
    const float* tb = cd + ((size_t)(bb*64 + f1*8 + f2))*4096;

    // stage: 1024 f4, 4/thread, identity
    #pragma unroll
    for (int i = 0; i < 4; ++i) {
        float4 v = *(const float4*)(tb + (t*4 + i)*4);
        *(float4*)&ld[(t*4 + i)*4] = v;
    }
    __syncthreads();

    const int oc0 = wid*24;
    float acc[24];
    #pragma unroll
    for (int j = 0; j < 24; j += 4) {
        float4 b = *(const float4*)(bp + oc0 + j);
        acc[j]=b.x; acc[j+1]=b.y; acc[j+2]=b.z; acc[j+3]=b.w;
    }

    #pragma unroll
    for (int he = 0; he < 8; ++he) {
        float2 sv = *(const float2*)&ld[3072 + he*128 + lane*2];
        int bi = (int)sv.y;
        const float* pr = &ld[he*384 + bi];
        #pragma unroll
        for (int j = 0; j < 24; ++j)
            acc[j] = fmaf(pr[(oc0 + j)*4], sv.x, acc[j]);
    }

    // epilogue: lane = n -> out[bb][oc][f1*8 + n>>3][f2*8 + (n&7)]
    const int r = lane >> 3, hh = lane & 7;
    const size_t ob = (size_t)bb*96*4096 + (size_t)(f1*8 + r)*64 + f2*8 + hh;
    #pragma unroll
    for (int j = 0; j < 24; ++j)
        out[ob + (size_t)(oc0 + j)*4096] = acc[j];
}

extern "C" void kernel_launch(void* const* d_in, const int* in_sizes, int n_in,
                              void* d_out, int out_size, void* d_ws, size_t ws_size,
                              hipStream_t stream) {
    (void)in_sizes; (void)n_in; (void)out_size; (void)ws_size;
    float* cd = (float*)d_ws;   // 1024 tiles x 4096 floats = 16 MiB
    cc_main<<<dim3(4096), dim3(TPB), 0, stream>>>(
        (const float*)d_in[0],  // x
        (const float*)d_in[1],  // Wf
        (const float*)d_in[2],  // bf
        (const float*)d_in[3],  // Wv
        (const float*)d_in[4],  // bv
        (const float*)d_in[5],  // Wp
        (const float*)d_in[7],  // sim_alpha
        (const float*)d_in[8],  // sim_beta
        cd);
    cc_comb<<<dim3(1024), dim3(TPB), 0, stream>>>(
        cd,
        (const float*)d_in[6],  // bp
        (float*)d_out);
}